// Round 14
// baseline (389.425 us; speedup 1.0000x reference)
//
#include <hip/hip_runtime.h>
#include <stdint.h>

// MGCN pipeline, R17 resubmit #6 (R16: 387.3us; adj 133.7us @ 43.2% Mfma ==
// R15 -> the asymmetric-buffer counted vmcnt changed NOTHING).  (R17 has not
// yet executed: broker timeouts x6 + container failure x1.  Identical source
// resubmitted -- broker failures precede kernel execution, so they are not
// kernel-correlated; keeping the R16->R17 A/B single-variable.)
// Falsification analysis: my barriers were asm volatile("s_barrier":::
// "memory") and waitcnts carried "memory" clobbers -> the AMDGPU waitcnt
// pass treats them as memory accesses and inserts its own s_waitcnt vmcnt(0)
// lgkmcnt(0) before EVERY phase barrier, silently restoring the full drain
// (explains R15==R16 and the serialized 2483+2260 cycle sum).
// R17: adopt the learn_hip m201 template's verified sync forms in adj_gemm:
//   __builtin_amdgcn_s_barrier() (no implicit drain), clobber-free
//   asm volatile("s_waitcnt vmcnt(4)") entry wait, explicit
//   asm volatile("s_waitcnt lgkmcnt(0)") after each phase barrier, one
//   __builtin_amdgcn_sched_barrier(0) after tile entry to pin ordering.
//   Buffers (A x2 + B x3 = 160KB), stage schedule, swizzle, epilogue
//   byte-identical to R16.
// Predicted: adj ~85-100us @ 55-65% Mfma, total ~340-355us.

typedef __attribute__((ext_vector_type(8))) short short8;
typedef __attribute__((ext_vector_type(4))) float floatx4;

__device__ __forceinline__ unsigned short f2bf(float f) {
    unsigned int x = __builtin_bit_cast(unsigned int, f);
    x += 0x7fffu + ((x >> 16) & 1u);   // RNE
    return (unsigned short)(x >> 16);
}
__device__ __forceinline__ float bf2f(unsigned short u) {
    return __builtin_bit_cast(float, (unsigned int)u << 16);
}

#define MODE_ATTR 0
#define MODE_TXS  3   // split-K partial: private slice write
#define MODE_SALL 4

// ---------------------------------------------------------------------------
// Generic bt-GEMM: C[i][j] = sum_k A[i][k]*Bt[j][k], bf16 in, f32 accum.
// Block 256 thr = 4 waves in 2x2, each wave 64x64 (4x4 mfma tiles).
// (m97-style 2-barrier loop; used for ATTR / TXS / SALL modes.)
// ---------------------------------------------------------------------------
__global__ __launch_bounds__(256, 3)
void gemm_bt(const unsigned short* __restrict__ A, const unsigned short* __restrict__ Bt,
             int lda, int ldb, int kchunk, int mode,
             float* __restrict__ fout, unsigned short* __restrict__ bout,
             const float* __restrict__ vecj, float* __restrict__ rsum)
{
    __shared__ __attribute__((aligned(16))) unsigned short As[128 * 32];
    __shared__ __attribute__((aligned(16))) unsigned short Bs[128 * 32];

    const int bx = blockIdx.x, by = blockIdx.y;
    const int m0  = by * 128;
    const int n0  = bx * 128;
    const int t   = threadIdx.x;
    const int w   = t >> 6;
    const int q   = (t & 63) >> 4;
    const int m16 = t & 15;
    const int wm  = (w & 1) * 64;
    const int wn  = (w >> 1) * 64;
    const int kbeg = blockIdx.z * kchunk;
    const int kend = kbeg + kchunk;

    floatx4 acc[4][4];
#pragma unroll
    for (int a = 0; a < 4; a++)
#pragma unroll
        for (int b = 0; b < 4; b++)
            acc[a][b] = (floatx4){0.f, 0.f, 0.f, 0.f};

    for (int k0 = kbeg; k0 < kend; k0 += 32) {
        __syncthreads();   // prev iteration's LDS reads complete
#pragma unroll
        for (int c = 0; c < 2; c++) {
            const int off    = (c * 256 + t) * 16;
            const int row    = off >> 6;
            const int colb   = off & 63;
            const int ldsoff = c * 4096 + w * 1024;
            const unsigned short* ga = A + (size_t)(m0 + row) * lda + k0 + (colb >> 1);
            __builtin_amdgcn_global_load_lds(
                (const __attribute__((address_space(1))) unsigned int*)ga,
                (__attribute__((address_space(3))) unsigned int*)((char*)As + ldsoff),
                16, 0, 0);
            const unsigned short* gb = Bt + (size_t)(n0 + row) * ldb + k0 + (colb >> 1);
            __builtin_amdgcn_global_load_lds(
                (const __attribute__((address_space(1))) unsigned int*)gb,
                (__attribute__((address_space(3))) unsigned int*)((char*)Bs + ldsoff),
                16, 0, 0);
        }
        __syncthreads();

        short8 af[4], bf[4];
#pragma unroll
        for (int mt = 0; mt < 4; mt++)
            af[mt] = *reinterpret_cast<const short8*>(&As[(wm + mt * 16 + m16) * 32 + q * 8]);
#pragma unroll
        for (int nt = 0; nt < 4; nt++)
            bf[nt] = *reinterpret_cast<const short8*>(&Bs[(wn + nt * 16 + m16) * 32 + q * 8]);
#pragma unroll
        for (int mt = 0; mt < 4; mt++)
#pragma unroll
            for (int nt = 0; nt < 4; nt++)
                acc[mt][nt] = __builtin_amdgcn_mfma_f32_16x16x32_bf16(af[mt], bf[nt], acc[mt][nt], 0, 0, 0);
    }

    // epilogue: C/D layout col = lane&15, row = q*4 + reg
    if (mode == MODE_ATTR) {
#pragma unroll
        for (int mt = 0; mt < 4; mt++)
#pragma unroll
            for (int r = 0; r < 4; r++) {
                const int i = m0 + wm + mt * 16 + q * 4 + r;
                float s = 0.f;
#pragma unroll
                for (int nt = 0; nt < 4; nt++) {
                    const int j = n0 + wn + nt * 16 + m16;
                    float v = acc[mt][nt][r] + vecj[j];
                    v = 1.0f / (1.0f + __expf(-v));
                    bout[(size_t)i * 4096 + j] = f2bf(v);
                    s += v * v;
                }
                s += __shfl_xor(s, 1);
                s += __shfl_xor(s, 2);
                s += __shfl_xor(s, 4);
                s += __shfl_xor(s, 8);
                if (m16 == 0) atomicAdd(&rsum[i], s);
            }
    } else {
#pragma unroll
        for (int mt = 0; mt < 4; mt++)
#pragma unroll
            for (int nt = 0; nt < 4; nt++)
#pragma unroll
                for (int r = 0; r < 4; r++) {
                    const int i = m0 + wm + mt * 16 + q * 4 + r;
                    const int j = n0 + wn + nt * 16 + m16;
                    float v = acc[mt][nt][r];
                    if (mode == MODE_TXS)
                        fout[(size_t)blockIdx.z * 1048576 + (size_t)i * 256 + j] = v;
                    else   // MODE_SALL
                        fout[(size_t)i * 640 + j] = v + vecj[j];
                }
    }
}

// ---------------------------------------------------------------------------
// adj GEMM: adj = (attr @ attr^T) * rninv_i * rninv_j, bf16 out (FULL matrix),
// fused row sum/max stats.
//   BM=BN=256, BK=64; 8 waves 2Mx4N, wave tile 128x64 (acc 8x4 frags).
//   LDS 160KB: A 2 bufs x 16384 ushort + B 3 bufs x 16384 ushort.
//   stage A(tt+1) @qd0, stage B(tt+2) @qd1 -> entry wait vmcnt(4) counted
//   (newest 4 outstanding = B(tt+1)); vmcnt(0) only at tt=63.
//   Sync ops are the m201-template forms: __builtin_amdgcn_s_barrier() (no
//   compiler-inserted drain), clobber-free waitcnt asm, explicit lgkmcnt(0)
//   per phase.  16B-slot XOR swizzle (slot ^ row&7) on global source +
//   ds_read (R14-R16 proven: SQ_LDS_BANK_CONFLICT = 0).
// ---------------------------------------------------------------------------
__global__ __launch_bounds__(512, 1)
void adj_gemm(const unsigned short* __restrict__ attr,
              unsigned short* __restrict__ bout,
              const float* __restrict__ rninv,
              float* __restrict__ rsum, unsigned int* __restrict__ rmaxu)
{
    // [A buf0 | A buf1 | B buf0 | B buf1 | B buf2], each 16384 ushort (32KB)
    __shared__ __attribute__((aligned(16))) unsigned short lds[5 * 16384];

    const int bx = blockIdx.x;          // 0..15 : 256-col n-tile
    const int by = blockIdx.y;          // 0..15 : 256-row m-tile
    const int m0 = by * 256;
    const int n0 = bx * 256;
    const int t  = threadIdx.x;         // 0..511
    const int w  = t >> 6;
    const int l  = t & 63;
    const int q  = l >> 4;
    const int m16 = l & 15;
    const int wm = (w >> 2) * 128;      // 0 or 128   (M-group)
    const int wn = (w & 3) * 64;        // 0,64,128,192 (N-group)

    floatx4 acc[8][4];                  // [fr = qd*2+mm][bn]
#pragma unroll
    for (int a = 0; a < 8; a++)
#pragma unroll
        for (int b = 0; b < 4; b++)
            acc[a][b] = (floatx4){0.f, 0.f, 0.f, 0.f};

    // stage one operand of K-tile tau:  A -> buf tau&1, B -> buf tau%3.
    // 4 x global_load_lds x 512 thr x 16B = 32KB (256 rows x 64 k).
    auto stage_op = [&](int tau, int isA) {
        unsigned short* base = isA ? &lds[(tau & 1) * 16384]
                                   : &lds[(2 + tau % 3) * 16384];
        const int rbase = isA ? m0 : n0;
#pragma unroll
        for (int c = 0; c < 4; c++) {
            const int s   = c * 512 + t;     // 16B slot, 0..2047
            const int row = s >> 3;          // 0..255
            const int g16 = (s & 7) ^ (row & 7);   // swizzled source block
            const unsigned short* g = attr + (size_t)(rbase + row) * 4096 + tau * 64 + g16 * 8;
            __builtin_amdgcn_global_load_lds(
                (const __attribute__((address_space(1))) unsigned int*)g,
                (__attribute__((address_space(3))) unsigned int*)((char*)base + s * 16),
                16, 0, 0);
        }
    };

    // prologue (issue order matters for the counted wait):
    //   A(0) [4], B(0) [4], B(1) [4]  -> at entry(0) vmcnt(4) leaves B(1).
    stage_op(0, 1);
    stage_op(0, 0);
    stage_op(1, 0);

    for (int tt = 0; tt < 64; tt++) {
        // counted entry wait: newest 4 outstanding loads are B(tt+1); A(tt),
        // B(tt) and older are forced complete.  Full drain only at tt=63.
        if (tt == 63) asm volatile("s_waitcnt vmcnt(0)");
        else          asm volatile("s_waitcnt vmcnt(4)");
        __builtin_amdgcn_s_barrier();
        __builtin_amdgcn_sched_barrier(0);   // pin reads below the entry wait

        const unsigned short* Ab = &lds[(tt & 1) * 16384];
        const unsigned short* Bb = &lds[(2 + tt % 3) * 16384];

        // B-frags for the wave's 64 cols x K=64: read once, live all 4 phases
        short8 bfr[4][2];
#pragma unroll
        for (int bn = 0; bn < 4; bn++) {
            const int row = wn + bn * 16 + m16;
#pragma unroll
            for (int kk = 0; kk < 2; kk++)
                bfr[bn][kk] = *reinterpret_cast<const short8*>(
                    &Bb[row * 64 + (((kk * 4 + q) ^ (row & 7)) * 8)]);
        }

#pragma unroll
        for (int qd = 0; qd < 4; qd++) {
            // A-frags for this 32-row quadrant
            short8 afr[2][2];
#pragma unroll
            for (int mm = 0; mm < 2; mm++) {
                const int row = wm + qd * 32 + mm * 16 + m16;
#pragma unroll
                for (int kk = 0; kk < 2; kk++)
                    afr[mm][kk] = *reinterpret_cast<const short8*>(
                        &Ab[row * 64 + (((kk * 4 + q) ^ (row & 7)) * 8)]);
            }
            if (qd == 0 && tt < 63) stage_op(tt + 1, 1);   // next A
            if (qd == 1 && tt < 62) stage_op(tt + 2, 0);   // next-next B
            __builtin_amdgcn_s_barrier();
            asm volatile("s_waitcnt lgkmcnt(0)");
            __builtin_amdgcn_s_setprio(1);
#pragma unroll
            for (int mm = 0; mm < 2; mm++)
#pragma unroll
                for (int bn = 0; bn < 4; bn++)
#pragma unroll
                    for (int kk = 0; kk < 2; kk++)
                        acc[qd * 2 + mm][bn] = __builtin_amdgcn_mfma_f32_16x16x32_bf16(
                            afr[mm][kk], bfr[bn][kk], acc[qd * 2 + mm][bn], 0, 0, 0);
            __builtin_amdgcn_s_setprio(0);
            __builtin_amdgcn_s_barrier();
        }
    }

    // ---- epilogue: C/D layout col = lane&15, row = q*4 + reg ----
    float vjv[4];
#pragma unroll
    for (int bn = 0; bn < 4; bn++)
        vjv[bn] = rninv[n0 + wn + bn * 16 + m16];
#pragma unroll
    for (int fr = 0; fr < 8; fr++) {
        const int rowb = m0 + wm + fr * 16 + q * 4;   // +r
        float vi[4];
#pragma unroll
        for (int r = 0; r < 4; r++) vi[r] = rninv[rowb + r];
        // bf16 store
#pragma unroll
        for (int bn = 0; bn < 4; bn++) {
            const int j = n0 + wn + bn * 16 + m16;
#pragma unroll
            for (int r = 0; r < 4; r++)
                bout[(size_t)(rowb + r) * 4096 + j] = f2bf(acc[fr][bn][r] * vi[r] * vjv[bn]);
        }
        // fused row stats over this wave's 64 cols
#pragma unroll
        for (int r = 0; r < 4; r++) {
            float s = 0.f, mx = 0.f;
#pragma unroll
            for (int bn = 0; bn < 4; bn++) {
                float b = acc[fr][bn][r] * vjv[bn];
                s += b; mx = fmaxf(mx, b);
            }
            s += __shfl_xor(s, 1);  mx = fmaxf(mx, __shfl_xor(mx, 1));
            s += __shfl_xor(s, 2);  mx = fmaxf(mx, __shfl_xor(mx, 2));
            s += __shfl_xor(s, 4);  mx = fmaxf(mx, __shfl_xor(mx, 4));
            s += __shfl_xor(s, 8);  mx = fmaxf(mx, __shfl_xor(mx, 8));
            if (m16 == 0) {
                atomicAdd(&rsum[rowb + r], s * vi[r]);
                atomicMax(&rmaxu[rowb + r], __float_as_uint(mx * vi[r]));
            }
        }
    }
}

// ---------------------------------------------------------------------------
// prep kernels
// ---------------------------------------------------------------------------
__global__ void prep_x(const float* __restrict__ x, unsigned short* __restrict__ xA,
                       unsigned short* __restrict__ TX) {
    const int i = blockIdx.x;
    const int t = threadIdx.x;
    if (t < 224) {
        float v = (t < 200) ? x[(size_t)i * 200 + t] : 0.f;
        unsigned short b = f2bf(v);
        xA[(size_t)i * 224 + t] = b;
        if (t < 200) TX[(size_t)i * 608 + t] = b;
    }
    if (t >= 224 && t < 232) TX[(size_t)i * 608 + 600 + (t - 224)] = 0;
}

__global__ void transpose_to_bf16(const float* __restrict__ in, int R, int C,
                                  unsigned short* __restrict__ out, int outRows, int ldo) {
    __shared__ float tile[32][33];
    const int c0 = blockIdx.x * 32;
    const int r0 = blockIdx.y * 32;
    const int tx = threadIdx.x, ty = threadIdx.y;  // 32 x 8
    for (int s = 0; s < 32; s += 8) {
        int r = r0 + ty + s, c = c0 + tx;
        tile[ty + s][tx] = (r < R && c < C) ? in[(size_t)r * C + c] : 0.f;
    }
    __syncthreads();
    for (int s = 0; s < 32; s += 8) {
        int orow = c0 + ty + s;
        int ocol = r0 + tx;
        if (orow < outRows && ocol < ldo)
            out[(size_t)orow * ldo + ocol] = f2bf(tile[tx][ty + s]);
    }
}

__global__ void prep_misc(const float* __restrict__ w1, const float* __restrict__ b1,
                          const float* __restrict__ w2, const float* __restrict__ b2,
                          const float* __restrict__ w3, const float* __restrict__ b3,
                          unsigned short* __restrict__ WallT, float* __restrict__ bias_all,
                          float* __restrict__ colsum, float* __restrict__ colsq,
                          float* __restrict__ rnsum, float* __restrict__ rowsum,
                          unsigned int* __restrict__ rowmaxu) {
    const int tid0 = blockIdx.x * 256 + threadIdx.x;
    const int stride = gridDim.x * 256;
    for (int p = tid0; p < 640 * 608; p += stride) {
        int n = p / 608, k = p % 608;
        float v = 0.f;
        if (n < 200)      { if (k < 200) v = w1[k * 200 + n]; }
        else if (n < 400) { if (k < 400) v = w2[k * 200 + (n - 200)]; }
        else if (n < 600) { if (k < 600) v = w3[k * 200 + (n - 400)]; }
        WallT[p] = f2bf(v);
    }
    for (int p = tid0; p < 640; p += stride) {
        float v = 0.f;
        if (p < 200) v = b1[p];
        else if (p < 400) v = b2[p - 200];
        else if (p < 600) v = b3[p - 400];
        bias_all[p] = v;
        colsum[p] = 0.f;
        colsq[p] = 0.f;
    }
    for (int p = tid0; p < 4096; p += stride) {
        rnsum[p] = 0.f;
        rowsum[p] = 0.f;
        rowmaxu[p] = 0u;
    }
}

// ---------------------------------------------------------------------------
// tiny finalizers
// ---------------------------------------------------------------------------
__global__ void finalize_rninv(const float* __restrict__ rnsum, float* __restrict__ rninv) {
    int i = blockIdx.x * 256 + threadIdx.x;
    if (i < 4096) rninv[i] = 1.0f / fmaxf(sqrtf(rnsum[i]), 1e-8f);
}

__global__ void dinv_finalize(const unsigned short* __restrict__ adjb,
                              const float* __restrict__ rowsum,
                              const unsigned int* __restrict__ rowmaxu,
                              float* __restrict__ rmaxinv, float* __restrict__ dinv) {
    int i = blockIdx.x * 256 + threadIdx.x;
    if (i >= 4096) return;
    float M = __uint_as_float(rowmaxu[i]);
    float diag = bf2f(adjb[(size_t)i * 4097]);
    float deg = (rowsum[i] - diag) / M;
    rmaxinv[i] = 1.0f / M;
    dinv[i] = (deg > 0.f) ? rsqrtf(deg) : 0.f;
}

// ---------------------------------------------------------------------------
// A_norm + W from bf16 FULL adj.  Tile 64x64, branch-free; W = transposed
// Laplacian through padded LDS.
// ---------------------------------------------------------------------------
__global__ void anorm_w2(const unsigned short* __restrict__ adjb,
                         const float* __restrict__ rmaxinv, const float* __restrict__ dinv,
                         float* __restrict__ An, unsigned short* __restrict__ W) {
    __shared__ float td[64][65];
    const int i0 = blockIdx.y * 64, j0 = blockIdx.x * 64;
    const int tx = threadIdx.x & 63, ty = threadIdx.x >> 6;
    const float dj = dinv[j0 + tx];
#pragma unroll
    for (int s = 0; s < 64; s += 4) {
        int i = i0 + s + ty;
        float a = bf2f(adjb[(size_t)i * 4096 + j0 + tx]) * rmaxinv[i];
        An[(size_t)i * 4096 + j0 + tx] = a;
        td[s + ty][tx] = (i == j0 + tx) ? 0.f : (-dinv[i] * dj * a);
    }
    __syncthreads();
#pragma unroll
    for (int s = 0; s < 64; s += 4) {
        int jr = j0 + s + ty;
        W[(size_t)jr * 4096 + i0 + tx] = f2bf(td[tx][s + ty]);
    }
}

// ---------------------------------------------------------------------------
// split-K converts (sum 8 slices of [4096][256])
// ---------------------------------------------------------------------------
__global__ void tx_convert1(const float* __restrict__ tf, int nslices,
                            unsigned short* __restrict__ TX,
                            unsigned short* __restrict__ tx1T) {
    __shared__ float tile[32][33];
    const int j0 = blockIdx.x * 32;
    const int i0 = blockIdx.y * 32;
    const int tx = threadIdx.x, ty = threadIdx.y;  // 32 x 8
    for (int s = 0; s < 32; s += 8) {
        int i = i0 + ty + s, j = j0 + tx;
        float v = 0.f;
        for (int z = 0; z < nslices; z++)
            v += tf[(size_t)z * 1048576 + (size_t)i * 256 + j];
        tile[ty + s][tx] = v;
        if (j < 200) TX[(size_t)i * 608 + 200 + j] = f2bf(v);
    }
    __syncthreads();
    for (int s = 0; s < 32; s += 8) {
        int jr = j0 + ty + s;
        int ic = i0 + tx;
        tx1T[(size_t)jr * 4096 + ic] = f2bf(tile[tx][ty + s]);
    }
}

__global__ void tx_convert2(const float* __restrict__ tf, int nslices,
                            const float* __restrict__ x,
                            unsigned short* __restrict__ TX) {
    int idx = blockIdx.x * 256 + threadIdx.x;
    if (idx >= 4096 * 200) return;
    int i = idx / 200, j = idx % 200;
    float v = 0.f;
    for (int z = 0; z < nslices; z++)
        v += tf[(size_t)z * 1048576 + (size_t)i * 256 + j];
    TX[(size_t)i * 608 + 400 + j] = f2bf(2.f * v - x[idx]);
}

// ---------------------------------------------------------------------------
// BatchNorm
// ---------------------------------------------------------------------------
__global__ void bn_partial(const float* __restrict__ sall, float* __restrict__ colsum,
                           float* __restrict__ colsq) {
    const int tx = threadIdx.x & 63, ty = threadIdx.x >> 6;
    const int c = blockIdx.x * 64 + tx;
    const int r0 = blockIdx.y * 256;
    float sm = 0.f, sq = 0.f;
    if (c < 600) {
        for (int s = 0; s < 256; s += 4) {
            float v = sall[(size_t)(r0 + s + ty) * 640 + c];
            sm += v; sq += v * v;
        }
    }
    __shared__ float ls[4][64], lq[4][64];
    ls[ty][tx] = sm; lq[ty][tx] = sq;
    __syncthreads();
    if (ty == 0 && c < 600) {
        atomicAdd(&colsum[c], ls[0][tx] + ls[1][tx] + ls[2][tx] + ls[3][tx]);
        atomicAdd(&colsq[c], lq[0][tx] + lq[1][tx] + lq[2][tx] + lq[3][tx]);
    }
}

__global__ void bn_write(const float* __restrict__ sall, const float* __restrict__ colsum,
                         const float* __restrict__ colsq, const float* __restrict__ gamma,
                         const float* __restrict__ beta, float* __restrict__ out) {
    const int tx = threadIdx.x & 63, ty = threadIdx.x >> 6;
    const int c = blockIdx.x * 64 + tx;
    if (c >= 600) return;
    const float mu  = colsum[c] * (1.f / 4096.f);
    float var = colsq[c] * (1.f / 4096.f) - mu * mu;
    var = fmaxf(var, 0.f);
    const float inv = rsqrtf(var + 1e-5f);
    const int cc = c % 200;
    const float g = gamma[cc] * inv, be = beta[cc];
    const size_t base = (size_t)(c / 200) * 819200;
    const int r0 = blockIdx.y * 256;
    for (int s = 0; s < 256; s += 4) {
        int r = r0 + s + ty;
        float v = sall[(size_t)r * 640 + c];
        out[base + (size_t)r * 200 + cc] = g * (v - mu) + be;
    }
}

// ---------------------------------------------------------------------------
extern "C" void kernel_launch(void* const* d_in, const int* in_sizes, int n_in,
                              void* d_out, int out_size, void* d_ws, size_t ws_size,
                              hipStream_t stream) {
    const float* x     = (const float*)d_in[0];
    const float* gglw  = (const float*)d_in[1];
    const float* gglb  = (const float*)d_in[2];
    const float* w1    = (const float*)d_in[3];
    const float* b1    = (const float*)d_in[4];
    const float* w2    = (const float*)d_in[5];
    const float* b2    = (const float*)d_in[6];
    const float* w3    = (const float*)d_in[7];
    const float* b3    = (const float*)d_in[8];
    const float* gamma = (const float*)d_in[9];
    const float* beta  = (const float*)d_in[10];
    float* out = (float*)d_out;

    char* ws = (char*)d_ws;
    size_t off = 0;
    auto alloc = [&](size_t bytes) -> void* {
        void* p = ws + off;
        off += (bytes + 255) & ~(size_t)255;
        return p;
    };
    unsigned short* TX    = (unsigned short*)alloc(4096ull * 608 * 2);
    unsigned short* WallT = (unsigned short*)alloc(640ull * 608 * 2);
    float*          sall  = (float*)alloc(4096ull * 640 * 4);
    float* bias_all = (float*)alloc(640 * 4);
    float* colsum   = (float*)alloc(640 * 4);
    float* colsq    = (float*)alloc(640 * 4);
    float* rnsum    = (float*)alloc(4096 * 4);
    float* rowsum   = (float*)alloc(4096 * 4);
    unsigned int* rowmaxu = (unsigned int*)alloc(4096 * 4);
    unsigned short* xA    = (unsigned short*)alloc(4096ull * 224 * 2);
    unsigned short* gglwT = (unsigned short*)alloc(4096ull * 224 * 2);
    unsigned short* xT    = (unsigned short*)alloc(256ull * 4096 * 2);
    unsigned short* tx1T  = (unsigned short*)alloc(256ull * 4096 * 2);
    float* rninv    = (float*)alloc(4096 * 4);
    float* rmaxinv  = (float*)alloc(4096 * 4);
    float* dinv     = (float*)alloc(4096 * 4);
    unsigned short* attrW = (unsigned short*)alloc(4096ull * 4096 * 2);  // attr, then W
    unsigned short* attr  = attrW;
    unsigned short* W     = attrW;
    float* txs = (float*)alloc(8ull * 1048576 * 4);       // 32MB: adjb, then slices
    unsigned short* adjb = (unsigned short*)txs;          // bf16 4096x4096 FULL
    float* adjAn = out + 2457600;      // A_norm f32 slot in d_out

    prep_misc<<<1024, 256, 0, stream>>>(w1, b1, w2, b2, w3, b3,
                                        WallT, bias_all, colsum, colsq,
                                        rnsum, rowsum, rowmaxu);
    prep_x<<<4096, 256, 0, stream>>>(x, xA, TX);
    transpose_to_bf16<<<dim3(8, 128), dim3(32, 8), 0, stream>>>(x, 4096, 200, xT, 256, 4096);
    transpose_to_bf16<<<dim3(128, 7), dim3(32, 8), 0, stream>>>(gglw, 200, 4096, gglwT, 4096, 224);

    // attr = sigmoid(x @ ggl_w + b), fused row-norm partials
    gemm_bt<<<dim3(32, 32), 256, 0, stream>>>(xA, gglwT, 224, 224, 224, MODE_ATTR,
                                              nullptr, attr, gglb, rnsum);
    finalize_rninv<<<16, 256, 0, stream>>>(rnsum, rninv);
    // adj (full matrix, bf16) + fused row stats -- template-sync kernel
    adj_gemm<<<dim3(16, 16), 512, 0, stream>>>(attr, adjb, rninv, rowsum, rowmaxu);
    dinv_finalize<<<16, 256, 0, stream>>>(adjb, rowsum, rowmaxu, rmaxinv, dinv);
    // A_norm (f32 output slot) + W (bf16, attr slab)
    anorm_w2<<<dim3(64, 64), 256, 0, stream>>>(adjb, rmaxinv, dinv, adjAn, W);

    // tx1 = M @ x  (split-K=8 into txs slices; adjb is dead now)
    gemm_bt<<<dim3(2, 32, 8), 256, 0, stream>>>(W, xT, 4096, 4096, 512, MODE_TXS,
                                                txs, nullptr, nullptr, nullptr);
    tx_convert1<<<dim3(8, 128), dim3(32, 8), 0, stream>>>(txs, 8, TX, tx1T);
    // tx2 = 2*(M @ tx1) - x
    gemm_bt<<<dim3(2, 32, 8), 256, 0, stream>>>(W, tx1T, 4096, 4096, 512, MODE_TXS,
                                                txs, nullptr, nullptr, nullptr);
    tx_convert2<<<3200, 256, 0, stream>>>(txs, 8, x, TX);
    // s_all = [tx0|tx1|tx2] @ Wall + bias_all
    gemm_bt<<<dim3(5, 32), 256, 0, stream>>>(TX, WallT, 608, 608, 608, MODE_SALL,
                                             sall, nullptr, bias_all, nullptr);
    bn_partial<<<dim3(10, 16), 256, 0, stream>>>(sall, colsum, colsq);
    bn_write<<<dim3(10, 16), 256, 0, stream>>>(sall, colsum, colsq, gamma, beta, out);
}

// Round 15
// 372.661 us; speedup vs baseline: 1.0450x; 1.0450x over previous
//
#include <hip/hip_runtime.h>
#include <stdint.h>

// MGCN pipeline, R18 (R15=R16=R17: adj 133.7-134.4us @ 43% Mfma -- THREE
// schedule variants identical => the per-phase barriers are the invariant
// limiter.  Cycle model: LDS 2311 + MFMA 2483 = 4794 ~= measured 5025 ->
// pure SUM, zero overlap.  m114 mechanism: MFMA/LDS overlap requires waves
// at DIFFERENT phases; my per-phase workgroup barriers lockstep all 8 waves
// into the same phase, so no wave ever has MFMA ready while another reads.
// Correctness audit: intra-tile barriers are unnecessary -- entry
// vmcnt(counted)+barrier covers staged-data visibility, and WAR on the
// rotated buffers is covered because each wave drains its own ds_reads
// (lgkmcnt before its last MFMA) before reaching the next entry barrier.
// R18: ONE barrier per K-tile (entry), counted vmcnt(4) kept; all per-phase
// barriers / forced lgkmcnt(0) / setprio / sched_barrier removed; plain C++
// body so the compiler emits fine-grained lgkmcnt (m97 asm evidence) and
// waves de-phase to overlap LDS with MFMA.
// Predicted: adj ~90-105us @ 55-65% Mfma, total ~345-360us.
// Decision rule: unchanged => intra-block overlap unreachable at this
// geometry -> pivot to the non-adj ~255us (fusion / launch gaps).

typedef __attribute__((ext_vector_type(8))) short short8;
typedef __attribute__((ext_vector_type(4))) float floatx4;

__device__ __forceinline__ unsigned short f2bf(float f) {
    unsigned int x = __builtin_bit_cast(unsigned int, f);
    x += 0x7fffu + ((x >> 16) & 1u);   // RNE
    return (unsigned short)(x >> 16);
}
__device__ __forceinline__ float bf2f(unsigned short u) {
    return __builtin_bit_cast(float, (unsigned int)u << 16);
}

#define MODE_ATTR 0
#define MODE_TXS  3   // split-K partial: private slice write
#define MODE_SALL 4

// ---------------------------------------------------------------------------
// Generic bt-GEMM: C[i][j] = sum_k A[i][k]*Bt[j][k], bf16 in, f32 accum.
// Block 256 thr = 4 waves in 2x2, each wave 64x64 (4x4 mfma tiles).
// (m97-style 2-barrier loop; used for ATTR / TXS / SALL modes.)
// ---------------------------------------------------------------------------
__global__ __launch_bounds__(256, 3)
void gemm_bt(const unsigned short* __restrict__ A, const unsigned short* __restrict__ Bt,
             int lda, int ldb, int kchunk, int mode,
             float* __restrict__ fout, unsigned short* __restrict__ bout,
             const float* __restrict__ vecj, float* __restrict__ rsum)
{
    __shared__ __attribute__((aligned(16))) unsigned short As[128 * 32];
    __shared__ __attribute__((aligned(16))) unsigned short Bs[128 * 32];

    const int bx = blockIdx.x, by = blockIdx.y;
    const int m0  = by * 128;
    const int n0  = bx * 128;
    const int t   = threadIdx.x;
    const int w   = t >> 6;
    const int q   = (t & 63) >> 4;
    const int m16 = t & 15;
    const int wm  = (w & 1) * 64;
    const int wn  = (w >> 1) * 64;
    const int kbeg = blockIdx.z * kchunk;
    const int kend = kbeg + kchunk;

    floatx4 acc[4][4];
#pragma unroll
    for (int a = 0; a < 4; a++)
#pragma unroll
        for (int b = 0; b < 4; b++)
            acc[a][b] = (floatx4){0.f, 0.f, 0.f, 0.f};

    for (int k0 = kbeg; k0 < kend; k0 += 32) {
        __syncthreads();   // prev iteration's LDS reads complete
#pragma unroll
        for (int c = 0; c < 2; c++) {
            const int off    = (c * 256 + t) * 16;
            const int row    = off >> 6;
            const int colb   = off & 63;
            const int ldsoff = c * 4096 + w * 1024;
            const unsigned short* ga = A + (size_t)(m0 + row) * lda + k0 + (colb >> 1);
            __builtin_amdgcn_global_load_lds(
                (const __attribute__((address_space(1))) unsigned int*)ga,
                (__attribute__((address_space(3))) unsigned int*)((char*)As + ldsoff),
                16, 0, 0);
            const unsigned short* gb = Bt + (size_t)(n0 + row) * ldb + k0 + (colb >> 1);
            __builtin_amdgcn_global_load_lds(
                (const __attribute__((address_space(1))) unsigned int*)gb,
                (__attribute__((address_space(3))) unsigned int*)((char*)Bs + ldsoff),
                16, 0, 0);
        }
        __syncthreads();

        short8 af[4], bf[4];
#pragma unroll
        for (int mt = 0; mt < 4; mt++)
            af[mt] = *reinterpret_cast<const short8*>(&As[(wm + mt * 16 + m16) * 32 + q * 8]);
#pragma unroll
        for (int nt = 0; nt < 4; nt++)
            bf[nt] = *reinterpret_cast<const short8*>(&Bs[(wn + nt * 16 + m16) * 32 + q * 8]);
#pragma unroll
        for (int mt = 0; mt < 4; mt++)
#pragma unroll
            for (int nt = 0; nt < 4; nt++)
                acc[mt][nt] = __builtin_amdgcn_mfma_f32_16x16x32_bf16(af[mt], bf[nt], acc[mt][nt], 0, 0, 0);
    }

    // epilogue: C/D layout col = lane&15, row = q*4 + reg
    if (mode == MODE_ATTR) {
#pragma unroll
        for (int mt = 0; mt < 4; mt++)
#pragma unroll
            for (int r = 0; r < 4; r++) {
                const int i = m0 + wm + mt * 16 + q * 4 + r;
                float s = 0.f;
#pragma unroll
                for (int nt = 0; nt < 4; nt++) {
                    const int j = n0 + wn + nt * 16 + m16;
                    float v = acc[mt][nt][r] + vecj[j];
                    v = 1.0f / (1.0f + __expf(-v));
                    bout[(size_t)i * 4096 + j] = f2bf(v);
                    s += v * v;
                }
                s += __shfl_xor(s, 1);
                s += __shfl_xor(s, 2);
                s += __shfl_xor(s, 4);
                s += __shfl_xor(s, 8);
                if (m16 == 0) atomicAdd(&rsum[i], s);
            }
    } else {
#pragma unroll
        for (int mt = 0; mt < 4; mt++)
#pragma unroll
            for (int nt = 0; nt < 4; nt++)
#pragma unroll
                for (int r = 0; r < 4; r++) {
                    const int i = m0 + wm + mt * 16 + q * 4 + r;
                    const int j = n0 + wn + nt * 16 + m16;
                    float v = acc[mt][nt][r];
                    if (mode == MODE_TXS)
                        fout[(size_t)blockIdx.z * 1048576 + (size_t)i * 256 + j] = v;
                    else   // MODE_SALL
                        fout[(size_t)i * 640 + j] = v + vecj[j];
                }
    }
}

// ---------------------------------------------------------------------------
// adj GEMM: adj = (attr @ attr^T) * rninv_i * rninv_j, bf16 out (FULL matrix),
// fused row sum/max stats.
//   BM=BN=256, BK=64; 8 waves 2Mx4N, wave tile 128x64 (acc 8x4 frags).
//   LDS 160KB: A 2 bufs x 16384 ushort + B 3 bufs x 16384 ushort.
//   stage A(tt+1), B(tt+2) inside tile body -> entry wait vmcnt(4) counted
//   (newest 4 outstanding = B(tt+1)); vmcnt(0) only at tt=63.
//   ONE barrier per K-tile (entry).  No intra-tile barriers: waves de-phase
//   so trailing waves' ds_reads overlap leading waves' MFMA (m114 mechanism);
//   compiler inserts fine-grained lgkmcnt per MFMA (m97 asm evidence).
//   16B-slot XOR swizzle (slot ^ row&7) on global source + ds_read
//   (R14-R17 proven: SQ_LDS_BANK_CONFLICT = 0).
// ---------------------------------------------------------------------------
__global__ __launch_bounds__(512, 1)
void adj_gemm(const unsigned short* __restrict__ attr,
              unsigned short* __restrict__ bout,
              const float* __restrict__ rninv,
              float* __restrict__ rsum, unsigned int* __restrict__ rmaxu)
{
    // [A buf0 | A buf1 | B buf0 | B buf1 | B buf2], each 16384 ushort (32KB)
    __shared__ __attribute__((aligned(16))) unsigned short lds[5 * 16384];

    const int bx = blockIdx.x;          // 0..15 : 256-col n-tile
    const int by = blockIdx.y;          // 0..15 : 256-row m-tile
    const int m0 = by * 256;
    const int n0 = bx * 256;
    const int t  = threadIdx.x;         // 0..511
    const int w  = t >> 6;
    const int l  = t & 63;
    const int q  = l >> 4;
    const int m16 = l & 15;
    const int wm = (w >> 2) * 128;      // 0 or 128   (M-group)
    const int wn = (w & 3) * 64;        // 0,64,128,192 (N-group)

    floatx4 acc[8][4];                  // [fr = qd*2+mm][bn]
#pragma unroll
    for (int a = 0; a < 8; a++)
#pragma unroll
        for (int b = 0; b < 4; b++)
            acc[a][b] = (floatx4){0.f, 0.f, 0.f, 0.f};

    // stage one operand of K-tile tau:  A -> buf tau&1, B -> buf tau%3.
    // 4 x global_load_lds x 512 thr x 16B = 32KB (256 rows x 64 k).
    auto stage_op = [&](int tau, int isA) {
        unsigned short* base = isA ? &lds[(tau & 1) * 16384]
                                   : &lds[(2 + tau % 3) * 16384];
        const int rbase = isA ? m0 : n0;
#pragma unroll
        for (int c = 0; c < 4; c++) {
            const int s   = c * 512 + t;     // 16B slot, 0..2047
            const int row = s >> 3;          // 0..255
            const int g16 = (s & 7) ^ (row & 7);   // swizzled source block
            const unsigned short* g = attr + (size_t)(rbase + row) * 4096 + tau * 64 + g16 * 8;
            __builtin_amdgcn_global_load_lds(
                (const __attribute__((address_space(1))) unsigned int*)g,
                (__attribute__((address_space(3))) unsigned int*)((char*)base + s * 16),
                16, 0, 0);
        }
    };

    // prologue (issue order matters for the counted wait):
    //   A(0) [4], B(0) [4], B(1) [4]  -> at entry(0) vmcnt(4) leaves B(1).
    stage_op(0, 1);
    stage_op(0, 0);
    stage_op(1, 0);

    for (int tt = 0; tt < 64; tt++) {
        // counted entry wait: newest 4 outstanding loads are B(tt+1); A(tt),
        // B(tt) and older are forced complete.  Full drain only at tt=63.
        if (tt == 63) asm volatile("s_waitcnt vmcnt(0)");
        else          asm volatile("s_waitcnt vmcnt(4)");
        __builtin_amdgcn_s_barrier();   // the ONLY barrier in the K-loop

        const unsigned short* Ab = &lds[(tt & 1) * 16384];
        const unsigned short* Bb = &lds[(2 + tt % 3) * 16384];

        // B-frags for the wave's 64 cols x K=64: read once, live whole tile
        short8 bfr[4][2];
#pragma unroll
        for (int bn = 0; bn < 4; bn++) {
            const int row = wn + bn * 16 + m16;
#pragma unroll
            for (int kk = 0; kk < 2; kk++)
                bfr[bn][kk] = *reinterpret_cast<const short8*>(
                    &Bb[row * 64 + (((kk * 4 + q) ^ (row & 7)) * 8)]);
        }
        if (tt < 63) stage_op(tt + 1, 1);   // next A (cannot hoist above barrier)

#pragma unroll
        for (int qd = 0; qd < 4; qd++) {
            // A-frags for this 32-row quadrant
            short8 afr[2][2];
#pragma unroll
            for (int mm = 0; mm < 2; mm++) {
                const int row = wm + qd * 32 + mm * 16 + m16;
#pragma unroll
                for (int kk = 0; kk < 2; kk++)
                    afr[mm][kk] = *reinterpret_cast<const short8*>(
                        &Ab[row * 64 + (((kk * 4 + q) ^ (row & 7)) * 8)]);
            }
            if (qd == 0 && tt < 62) stage_op(tt + 2, 0);   // next-next B
#pragma unroll
            for (int mm = 0; mm < 2; mm++)
#pragma unroll
                for (int bn = 0; bn < 4; bn++)
#pragma unroll
                    for (int kk = 0; kk < 2; kk++)
                        acc[qd * 2 + mm][bn] = __builtin_amdgcn_mfma_f32_16x16x32_bf16(
                            afr[mm][kk], bfr[bn][kk], acc[qd * 2 + mm][bn], 0, 0, 0);
        }
    }

    // ---- epilogue: C/D layout col = lane&15, row = q*4 + reg ----
    float vjv[4];
#pragma unroll
    for (int bn = 0; bn < 4; bn++)
        vjv[bn] = rninv[n0 + wn + bn * 16 + m16];
#pragma unroll
    for (int fr = 0; fr < 8; fr++) {
        const int rowb = m0 + wm + fr * 16 + q * 4;   // +r
        float vi[4];
#pragma unroll
        for (int r = 0; r < 4; r++) vi[r] = rninv[rowb + r];
        // bf16 store
#pragma unroll
        for (int bn = 0; bn < 4; bn++) {
            const int j = n0 + wn + bn * 16 + m16;
#pragma unroll
            for (int r = 0; r < 4; r++)
                bout[(size_t)(rowb + r) * 4096 + j] = f2bf(acc[fr][bn][r] * vi[r] * vjv[bn]);
        }
        // fused row stats over this wave's 64 cols
#pragma unroll
        for (int r = 0; r < 4; r++) {
            float s = 0.f, mx = 0.f;
#pragma unroll
            for (int bn = 0; bn < 4; bn++) {
                float b = acc[fr][bn][r] * vjv[bn];
                s += b; mx = fmaxf(mx, b);
            }
            s += __shfl_xor(s, 1);  mx = fmaxf(mx, __shfl_xor(mx, 1));
            s += __shfl_xor(s, 2);  mx = fmaxf(mx, __shfl_xor(mx, 2));
            s += __shfl_xor(s, 4);  mx = fmaxf(mx, __shfl_xor(mx, 4));
            s += __shfl_xor(s, 8);  mx = fmaxf(mx, __shfl_xor(mx, 8));
            if (m16 == 0) {
                atomicAdd(&rsum[rowb + r], s * vi[r]);
                atomicMax(&rmaxu[rowb + r], __float_as_uint(mx * vi[r]));
            }
        }
    }
}

// ---------------------------------------------------------------------------
// prep kernels
// ---------------------------------------------------------------------------
__global__ void prep_x(const float* __restrict__ x, unsigned short* __restrict__ xA,
                       unsigned short* __restrict__ TX) {
    const int i = blockIdx.x;
    const int t = threadIdx.x;
    if (t < 224) {
        float v = (t < 200) ? x[(size_t)i * 200 + t] : 0.f;
        unsigned short b = f2bf(v);
        xA[(size_t)i * 224 + t] = b;
        if (t < 200) TX[(size_t)i * 608 + t] = b;
    }
    if (t >= 224 && t < 232) TX[(size_t)i * 608 + 600 + (t - 224)] = 0;
}

__global__ void transpose_to_bf16(const float* __restrict__ in, int R, int C,
                                  unsigned short* __restrict__ out, int outRows, int ldo) {
    __shared__ float tile[32][33];
    const int c0 = blockIdx.x * 32;
    const int r0 = blockIdx.y * 32;
    const int tx = threadIdx.x, ty = threadIdx.y;  // 32 x 8
    for (int s = 0; s < 32; s += 8) {
        int r = r0 + ty + s, c = c0 + tx;
        tile[ty + s][tx] = (r < R && c < C) ? in[(size_t)r * C + c] : 0.f;
    }
    __syncthreads();
    for (int s = 0; s < 32; s += 8) {
        int orow = c0 + ty + s;
        int ocol = r0 + tx;
        if (orow < outRows && ocol < ldo)
            out[(size_t)orow * ldo + ocol] = f2bf(tile[tx][ty + s]);
    }
}

__global__ void prep_misc(const float* __restrict__ w1, const float* __restrict__ b1,
                          const float* __restrict__ w2, const float* __restrict__ b2,
                          const float* __restrict__ w3, const float* __restrict__ b3,
                          unsigned short* __restrict__ WallT, float* __restrict__ bias_all,
                          float* __restrict__ colsum, float* __restrict__ colsq,
                          float* __restrict__ rnsum, float* __restrict__ rowsum,
                          unsigned int* __restrict__ rowmaxu) {
    const int tid0 = blockIdx.x * 256 + threadIdx.x;
    const int stride = gridDim.x * 256;
    for (int p = tid0; p < 640 * 608; p += stride) {
        int n = p / 608, k = p % 608;
        float v = 0.f;
        if (n < 200)      { if (k < 200) v = w1[k * 200 + n]; }
        else if (n < 400) { if (k < 400) v = w2[k * 200 + (n - 200)]; }
        else if (n < 600) { if (k < 600) v = w3[k * 200 + (n - 400)]; }
        WallT[p] = f2bf(v);
    }
    for (int p = tid0; p < 640; p += stride) {
        float v = 0.f;
        if (p < 200) v = b1[p];
        else if (p < 400) v = b2[p - 200];
        else if (p < 600) v = b3[p - 400];
        bias_all[p] = v;
        colsum[p] = 0.f;
        colsq[p] = 0.f;
    }
    for (int p = tid0; p < 4096; p += stride) {
        rnsum[p] = 0.f;
        rowsum[p] = 0.f;
        rowmaxu[p] = 0u;
    }
}

// ---------------------------------------------------------------------------
// tiny finalizers
// ---------------------------------------------------------------------------
__global__ void finalize_rninv(const float* __restrict__ rnsum, float* __restrict__ rninv) {
    int i = blockIdx.x * 256 + threadIdx.x;
    if (i < 4096) rninv[i] = 1.0f / fmaxf(sqrtf(rnsum[i]), 1e-8f);
}

__global__ void dinv_finalize(const unsigned short* __restrict__ adjb,
                              const float* __restrict__ rowsum,
                              const unsigned int* __restrict__ rowmaxu,
                              float* __restrict__ rmaxinv, float* __restrict__ dinv) {
    int i = blockIdx.x * 256 + threadIdx.x;
    if (i >= 4096) return;
    float M = __uint_as_float(rowmaxu[i]);
    float diag = bf2f(adjb[(size_t)i * 4097]);
    float deg = (rowsum[i] - diag) / M;
    rmaxinv[i] = 1.0f / M;
    dinv[i] = (deg > 0.f) ? rsqrtf(deg) : 0.f;
}

// ---------------------------------------------------------------------------
// A_norm + W from bf16 FULL adj.  Tile 64x64, branch-free; W = transposed
// Laplacian through padded LDS.
// ---------------------------------------------------------------------------
__global__ void anorm_w2(const unsigned short* __restrict__ adjb,
                         const float* __restrict__ rmaxinv, const float* __restrict__ dinv,
                         float* __restrict__ An, unsigned short* __restrict__ W) {
    __shared__ float td[64][65];
    const int i0 = blockIdx.y * 64, j0 = blockIdx.x * 64;
    const int tx = threadIdx.x & 63, ty = threadIdx.x >> 6;
    const float dj = dinv[j0 + tx];
#pragma unroll
    for (int s = 0; s < 64; s += 4) {
        int i = i0 + s + ty;
        float a = bf2f(adjb[(size_t)i * 4096 + j0 + tx]) * rmaxinv[i];
        An[(size_t)i * 4096 + j0 + tx] = a;
        td[s + ty][tx] = (i == j0 + tx) ? 0.f : (-dinv[i] * dj * a);
    }
    __syncthreads();
#pragma unroll
    for (int s = 0; s < 64; s += 4) {
        int jr = j0 + s + ty;
        W[(size_t)jr * 4096 + i0 + tx] = f2bf(td[tx][s + ty]);
    }
}

// ---------------------------------------------------------------------------
// split-K converts (sum 8 slices of [4096][256])
// ---------------------------------------------------------------------------
__global__ void tx_convert1(const float* __restrict__ tf, int nslices,
                            unsigned short* __restrict__ TX,
                            unsigned short* __restrict__ tx1T) {
    __shared__ float tile[32][33];
    const int j0 = blockIdx.x * 32;
    const int i0 = blockIdx.y * 32;
    const int tx = threadIdx.x, ty = threadIdx.y;  // 32 x 8
    for (int s = 0; s < 32; s += 8) {
        int i = i0 + ty + s, j = j0 + tx;
        float v = 0.f;
        for (int z = 0; z < nslices; z++)
            v += tf[(size_t)z * 1048576 + (size_t)i * 256 + j];
        tile[ty + s][tx] = v;
        if (j < 200) TX[(size_t)i * 608 + 200 + j] = f2bf(v);
    }
    __syncthreads();
    for (int s = 0; s < 32; s += 8) {
        int jr = j0 + ty + s;
        int ic = i0 + tx;
        tx1T[(size_t)jr * 4096 + ic] = f2bf(tile[tx][ty + s]);
    }
}

__global__ void tx_convert2(const float* __restrict__ tf, int nslices,
                            const float* __restrict__ x,
                            unsigned short* __restrict__ TX) {
    int idx = blockIdx.x * 256 + threadIdx.x;
    if (idx >= 4096 * 200) return;
    int i = idx / 200, j = idx % 200;
    float v = 0.f;
    for (int z = 0; z < nslices; z++)
        v += tf[(size_t)z * 1048576 + (size_t)i * 256 + j];
    TX[(size_t)i * 608 + 400 + j] = f2bf(2.f * v - x[idx]);
}

// ---------------------------------------------------------------------------
// BatchNorm
// ---------------------------------------------------------------------------
__global__ void bn_partial(const float* __restrict__ sall, float* __restrict__ colsum,
                           float* __restrict__ colsq) {
    const int tx = threadIdx.x & 63, ty = threadIdx.x >> 6;
    const int c = blockIdx.x * 64 + tx;
    const int r0 = blockIdx.y * 256;
    float sm = 0.f, sq = 0.f;
    if (c < 600) {
        for (int s = 0; s < 256; s += 4) {
            float v = sall[(size_t)(r0 + s + ty) * 640 + c];
            sm += v; sq += v * v;
        }
    }
    __shared__ float ls[4][64], lq[4][64];
    ls[ty][tx] = sm; lq[ty][tx] = sq;
    __syncthreads();
    if (ty == 0 && c < 600) {
        atomicAdd(&colsum[c], ls[0][tx] + ls[1][tx] + ls[2][tx] + ls[3][tx]);
        atomicAdd(&colsq[c], lq[0][tx] + lq[1][tx] + lq[2][tx] + lq[3][tx]);
    }
}

__global__ void bn_write(const float* __restrict__ sall, const float* __restrict__ colsum,
                         const float* __restrict__ colsq, const float* __restrict__ gamma,
                         const float* __restrict__ beta, float* __restrict__ out) {
    const int tx = threadIdx.x & 63, ty = threadIdx.x >> 6;
    const int c = blockIdx.x * 64 + tx;
    if (c >= 600) return;
    const float mu  = colsum[c] * (1.f / 4096.f);
    float var = colsq[c] * (1.f / 4096.f) - mu * mu;
    var = fmaxf(var, 0.f);
    const float inv = rsqrtf(var + 1e-5f);
    const int cc = c % 200;
    const float g = gamma[cc] * inv, be = beta[cc];
    const size_t base = (size_t)(c / 200) * 819200;
    const int r0 = blockIdx.y * 256;
    for (int s = 0; s < 256; s += 4) {
        int r = r0 + s + ty;
        float v = sall[(size_t)r * 640 + c];
        out[base + (size_t)r * 200 + cc] = g * (v - mu) + be;
    }
}

// ---------------------------------------------------------------------------
extern "C" void kernel_launch(void* const* d_in, const int* in_sizes, int n_in,
                              void* d_out, int out_size, void* d_ws, size_t ws_size,
                              hipStream_t stream) {
    const float* x     = (const float*)d_in[0];
    const float* gglw  = (const float*)d_in[1];
    const float* gglb  = (const float*)d_in[2];
    const float* w1    = (const float*)d_in[3];
    const float* b1    = (const float*)d_in[4];
    const float* w2    = (const float*)d_in[5];
    const float* b2    = (const float*)d_in[6];
    const float* w3    = (const float*)d_in[7];
    const float* b3    = (const float*)d_in[8];
    const float* gamma = (const float*)d_in[9];
    const float* beta  = (const float*)d_in[10];
    float* out = (float*)d_out;

    char* ws = (char*)d_ws;
    size_t off = 0;
    auto alloc = [&](size_t bytes) -> void* {
        void* p = ws + off;
        off += (bytes + 255) & ~(size_t)255;
        return p;
    };
    unsigned short* TX    = (unsigned short*)alloc(4096ull * 608 * 2);
    unsigned short* WallT = (unsigned short*)alloc(640ull * 608 * 2);
    float*          sall  = (float*)alloc(4096ull * 640 * 4);
    float* bias_all = (float*)alloc(640 * 4);
    float* colsum   = (float*)alloc(640 * 4);
    float* colsq    = (float*)alloc(640 * 4);
    float* rnsum    = (float*)alloc(4096 * 4);
    float* rowsum   = (float*)alloc(4096 * 4);
    unsigned int* rowmaxu = (unsigned int*)alloc(4096 * 4);
    unsigned short* xA    = (unsigned short*)alloc(4096ull * 224 * 2);
    unsigned short* gglwT = (unsigned short*)alloc(4096ull * 224 * 2);
    unsigned short* xT    = (unsigned short*)alloc(256ull * 4096 * 2);
    unsigned short* tx1T  = (unsigned short*)alloc(256ull * 4096 * 2);
    float* rninv    = (float*)alloc(4096 * 4);
    float* rmaxinv  = (float*)alloc(4096 * 4);
    float* dinv     = (float*)alloc(4096 * 4);
    unsigned short* attrW = (unsigned short*)alloc(4096ull * 4096 * 2);  // attr, then W
    unsigned short* attr  = attrW;
    unsigned short* W     = attrW;
    float* txs = (float*)alloc(8ull * 1048576 * 4);       // 32MB: adjb, then slices
    unsigned short* adjb = (unsigned short*)txs;          // bf16 4096x4096 FULL
    float* adjAn = out + 2457600;      // A_norm f32 slot in d_out

    prep_misc<<<1024, 256, 0, stream>>>(w1, b1, w2, b2, w3, b3,
                                        WallT, bias_all, colsum, colsq,
                                        rnsum, rowsum, rowmaxu);
    prep_x<<<4096, 256, 0, stream>>>(x, xA, TX);
    transpose_to_bf16<<<dim3(8, 128), dim3(32, 8), 0, stream>>>(x, 4096, 200, xT, 256, 4096);
    transpose_to_bf16<<<dim3(128, 7), dim3(32, 8), 0, stream>>>(gglw, 200, 4096, gglwT, 4096, 224);

    // attr = sigmoid(x @ ggl_w + b), fused row-norm partials
    gemm_bt<<<dim3(32, 32), 256, 0, stream>>>(xA, gglwT, 224, 224, 224, MODE_ATTR,
                                              nullptr, attr, gglb, rnsum);
    finalize_rninv<<<16, 256, 0, stream>>>(rnsum, rninv);
    // adj (full matrix, bf16) + fused row stats -- single-barrier kernel
    adj_gemm<<<dim3(16, 16), 512, 0, stream>>>(attr, adjb, rninv, rowsum, rowmaxu);
    dinv_finalize<<<16, 256, 0, stream>>>(adjb, rowsum, rowmaxu, rmaxinv, dinv);
    // A_norm (f32 output slot) + W (bf16, attr slab)
    anorm_w2<<<dim3(64, 64), 256, 0, stream>>>(adjb, rmaxinv, dinv, adjAn, W);

    // tx1 = M @ x  (split-K=8 into txs slices; adjb is dead now)
    gemm_bt<<<dim3(2, 32, 8), 256, 0, stream>>>(W, xT, 4096, 4096, 512, MODE_TXS,
                                                txs, nullptr, nullptr, nullptr);
    tx_convert1<<<dim3(8, 128), dim3(32, 8), 0, stream>>>(txs, 8, TX, tx1T);
    // tx2 = 2*(M @ tx1) - x
    gemm_bt<<<dim3(2, 32, 8), 256, 0, stream>>>(W, tx1T, 4096, 4096, 512, MODE_TXS,
                                                txs, nullptr, nullptr, nullptr);
    tx_convert2<<<3200, 256, 0, stream>>>(txs, 8, x, TX);
    // s_all = [tx0|tx1|tx2] @ Wall + bias_all
    gemm_bt<<<dim3(5, 32), 256, 0, stream>>>(TX, WallT, 608, 608, 608, MODE_SALL,
                                             sall, nullptr, bias_all, nullptr);
    bn_partial<<<dim3(10, 16), 256, 0, stream>>>(sall, colsum, colsq);
    bn_write<<<dim3(10, 16), 256, 0, stream>>>(sall, colsum, colsq, gamma, beta, out);
}